// Round 5
// baseline (18269.373 us; speedup 1.0000x reference)
//
#include <hip/hip_runtime.h>
#include <cmath>

#define S_LEN 32
#define E_DIM 128
#define H_DIM 256
#define V_DIM 512

__device__ __forceinline__ float sigf(float x) { return 1.0f / (1.0f + expf(-x)); }

// ---------------------------------------------------------------------------
// Row-persistent seq2seq: each block owns 8 batch rows through ALL 80 steps.
// 256 blocks x 512 threads. Thread (n = tid>>1, half = tid&1) owns hidden
// unit n of rows half*4..half*4+3: computes all 4 gates, keeps c in regs,
// writes h into LDS. Decoder logits+argmax are block-local (thread = vocab
// col). No global state, no grid sync, ONE kernel launch.
// All FMA chains k-ascending per output -> bit-identical to rounds 1-4.
// ---------------------------------------------------------------------------
__launch_bounds__(512)
__global__ void seq2seq_rowblock(
    const int* __restrict__ source,
    const float* __restrict__ enc_emb, const float* __restrict__ enc_Wih,
    const float* __restrict__ enc_Whh, const float* __restrict__ enc_bih,
    const float* __restrict__ enc_bhh,
    const float* __restrict__ dec_emb, const float* __restrict__ dec_Wih,
    const float* __restrict__ dec_Whh, const float* __restrict__ dec_bih,
    const float* __restrict__ dec_bhh,
    const float* __restrict__ fc_W, const float* __restrict__ fc_b,
    float* __restrict__ out, int T)
{
  __shared__ float A[8][388];     // [row][k], k 0..127 = emb, 128..383 = h
  __shared__ float bv[8][V_DIM];  // argmax candidates
  __shared__ int   toks[8];

  const int tid   = threadIdx.x;
  const int n     = tid >> 1;     // hidden unit 0..255
  const int rbase = (tid & 1) * 4;
  const int r0    = blockIdx.x * 8;

  float c_reg[4] = {0.f, 0.f, 0.f, 0.f};

  // ---- init: zero h-section of A, zero tokens (<SOS> = 0)
  #pragma unroll
  for (int s = 0; s < 4; ++s) {
    int w = s * 512 + tid;        // 0..2047 over 8 rows x 256 h
    A[w >> 8][E_DIM + (w & 255)] = 0.f;
  }
  if (tid < 8) toks[tid] = 0;

  // ---- per-thread bias sums for unit n (i,f,g,o)
  float ebs[4], dbs[4];
  #pragma unroll
  for (int g = 0; g < 4; ++g) {
    ebs[g] = enc_bih[g * H_DIM + n] + enc_bhh[g * H_DIM + n];
    dbs[g] = dec_bih[g * H_DIM + n] + dec_bhh[g * H_DIM + n];
  }

  const int nsteps = S_LEN + T;
  for (int step = 0; step < nsteps; ++step) {
    const bool enc = (step < S_LEN);
    const float* emb = enc ? enc_emb : dec_emb;
    const float* Wih = enc ? enc_Wih : dec_Wih;
    const float* Whh = enc ? enc_Whh : dec_Whh;

    __syncthreads();              // B1: prev h/tokens final; A-emb reusable

    // ---- stage x = emb[token] into A[.][0..127]  (256 float4, threads 0..255)
    if (tid < 256) {
      int row = tid >> 5, q = tid & 31;
      int token = enc ? source[(size_t)(r0 + row) * S_LEN + step] : toks[row];
      *(float4*)&A[row][q * 4] = *(const float4*)(emb + (size_t)token * E_DIM + q * 4);
    }
    __syncthreads();              // B2: A fully staged

    // ---- gates GEMM: acc[r][g] = sum_k A[rbase+r][k] * W[g*256+n][k]
    const float* pW[4];
    const float* pV[4];
    #pragma unroll
    for (int g = 0; g < 4; ++g) {
      pW[g] = Wih + (size_t)(g * H_DIM + n) * E_DIM;
      pV[g] = Whh + (size_t)(g * H_DIM + n) * H_DIM;
    }

    float acc[4][4] = {};         // [row][gate]
    float4 wc[4], wn[4];
    #pragma unroll
    for (int g = 0; g < 4; ++g) wc[g] = *(const float4*)(pW[g]);

    #pragma unroll 1
    for (int k0 = 0; k0 < E_DIM; k0 += 4) {   // emb part (Wih)
      #pragma unroll
      for (int g = 0; g < 4; ++g)
        wn[g] = (k0 + 4 < E_DIM) ? *(const float4*)(pW[g] + k0 + 4)
                                 : *(const float4*)(pV[g]);       // seam prefetch
      float4 a[4];
      #pragma unroll
      for (int r = 0; r < 4; ++r) a[r] = *(const float4*)&A[rbase + r][k0];
      #pragma unroll
      for (int r = 0; r < 4; ++r)
        #pragma unroll
        for (int g = 0; g < 4; ++g) {
          acc[r][g] = fmaf(a[r].x, wc[g].x, acc[r][g]);
          acc[r][g] = fmaf(a[r].y, wc[g].y, acc[r][g]);
          acc[r][g] = fmaf(a[r].z, wc[g].z, acc[r][g]);
          acc[r][g] = fmaf(a[r].w, wc[g].w, acc[r][g]);
        }
      #pragma unroll
      for (int g = 0; g < 4; ++g) wc[g] = wn[g];
    }

    #pragma unroll 1
    for (int k0 = 0; k0 < H_DIM; k0 += 4) {   // h part (Whh)
      #pragma unroll
      for (int g = 0; g < 4; ++g)
        wn[g] = (k0 + 4 < H_DIM) ? *(const float4*)(pV[g] + k0 + 4) : wc[g];
      float4 a[4];
      #pragma unroll
      for (int r = 0; r < 4; ++r) a[r] = *(const float4*)&A[rbase + r][E_DIM + k0];
      #pragma unroll
      for (int r = 0; r < 4; ++r)
        #pragma unroll
        for (int g = 0; g < 4; ++g) {
          acc[r][g] = fmaf(a[r].x, wc[g].x, acc[r][g]);
          acc[r][g] = fmaf(a[r].y, wc[g].y, acc[r][g]);
          acc[r][g] = fmaf(a[r].z, wc[g].z, acc[r][g]);
          acc[r][g] = fmaf(a[r].w, wc[g].w, acc[r][g]);
        }
      #pragma unroll
      for (int g = 0; g < 4; ++g) wc[g] = wn[g];
    }

    __syncthreads();              // B3: all A-h reads done before overwrite

    // ---- cell update (bit-identical formulas), h -> LDS
    #pragma unroll
    for (int r = 0; r < 4; ++r) {
      float zi = acc[r][0] + (enc ? ebs[0] : dbs[0]);
      float zf = acc[r][1] + (enc ? ebs[1] : dbs[1]);
      float zg = acc[r][2] + (enc ? ebs[2] : dbs[2]);
      float zo = acc[r][3] + (enc ? ebs[3] : dbs[3]);
      float cn = sigf(zf) * c_reg[r] + sigf(zi) * tanhf(zg);
      c_reg[r] = cn;
      A[rbase + r][E_DIM + n] = sigf(zo) * tanhf(cn);
    }

    // ---- decoder: logits + argmax (block-local)
    if (!enc) {
      const int t = step - S_LEN;
      __syncthreads();            // B4: h ready in A

      const float* pF = fc_W + (size_t)tid * H_DIM;   // thread = vocab col
      float dacc[8] = {};
      float4 b0c = *(const float4*)(pF);
      float4 b1c = *(const float4*)(pF + 4);
      #pragma unroll 1
      for (int k0 = 0; k0 < H_DIM; k0 += 8) {
        int kn = (k0 + 8 < H_DIM) ? k0 + 8 : 0;
        float4 b0n = *(const float4*)(pF + kn);
        float4 b1n = *(const float4*)(pF + kn + 4);
        #pragma unroll
        for (int r = 0; r < 8; ++r) {
          float4 a0 = *(const float4*)&A[r][E_DIM + k0];
          float4 a1 = *(const float4*)&A[r][E_DIM + k0 + 4];
          dacc[r] = fmaf(a0.x, b0c.x, dacc[r]);
          dacc[r] = fmaf(a0.y, b0c.y, dacc[r]);
          dacc[r] = fmaf(a0.z, b0c.z, dacc[r]);
          dacc[r] = fmaf(a0.w, b0c.w, dacc[r]);
          dacc[r] = fmaf(a1.x, b1c.x, dacc[r]);
          dacc[r] = fmaf(a1.y, b1c.y, dacc[r]);
          dacc[r] = fmaf(a1.z, b1c.z, dacc[r]);
          dacc[r] = fmaf(a1.w, b1c.w, dacc[r]);
        }
        b0c = b0n; b1c = b1n;
      }

      const float fb = fc_b[tid];
      #pragma unroll
      for (int r = 0; r < 8; ++r) {
        float z = dacc[r] + fb;
        out[((size_t)(r0 + r) * T + t) * V_DIM + tid] = z;
        bv[r][tid] = z;
      }
      __syncthreads();            // B5: candidates staged

      // wave w reduces row w (8 waves, 8 rows); first-index tie-break
      {
        const int wv = tid >> 6, lane = tid & 63;
        float best = bv[wv][lane];
        int   bix  = lane;
        #pragma unroll
        for (int m = 1; m < 8; ++m) {
          float v2 = bv[wv][lane + 64 * m];
          if (v2 > best) { best = v2; bix = lane + 64 * m; }  // ascending idx
        }
        #pragma unroll
        for (int off = 32; off; off >>= 1) {
          float ov = __shfl_xor(best, off);
          int   oi = __shfl_xor(bix, off);
          if (ov > best || (ov == best && oi < bix)) { best = ov; bix = oi; }
        }
        if (lane == 0) toks[wv] = bix;
      }
    }
  }
}

extern "C" void kernel_launch(void* const* d_in, const int* in_sizes, int n_in,
                              void* d_out, int out_size, void* d_ws, size_t ws_size,
                              hipStream_t stream) {
  const int*   source  = (const int*)d_in[0];
  const float* enc_emb = (const float*)d_in[2];
  const float* enc_Wih = (const float*)d_in[3];
  const float* enc_Whh = (const float*)d_in[4];
  const float* enc_bih = (const float*)d_in[5];
  const float* enc_bhh = (const float*)d_in[6];
  const float* dec_emb = (const float*)d_in[7];
  const float* dec_Wih = (const float*)d_in[8];
  const float* dec_Whh = (const float*)d_in[9];
  const float* dec_bih = (const float*)d_in[10];
  const float* dec_bhh = (const float*)d_in[11];
  const float* fc_W    = (const float*)d_in[12];
  const float* fc_b    = (const float*)d_in[13];
  float* out = (float*)d_out;

  const int B = in_sizes[0] / S_LEN;              // 2048
  const int T = out_size / (B * V_DIM);           // 48

  seq2seq_rowblock<<<dim3(B / 8), dim3(512), 0, stream>>>(
      source,
      enc_emb, enc_Wih, enc_Whh, enc_bih, enc_bhh,
      dec_emb, dec_Wih, dec_Whh, dec_bih, dec_bhh,
      fc_W, fc_b, out, T);
}

// Round 7
// 6515.258 us; speedup vs baseline: 2.8041x; 2.8041x over previous
//
#include <hip/hip_runtime.h>
#include <cmath>

#define S_LEN 32
#define E_DIM 128
#define H_DIM 256
#define V_DIM 512
#define KW    1152          // W cols per row: [w1|w2|w3] bf16 levels
#define AP    392           // A LDS pitch (shorts) -> 784 B
#define BP    72            // B LDS pitch (shorts) -> 144 B

typedef __attribute__((ext_vector_type(8))) short bf16x8v;
typedef __attribute__((ext_vector_type(4))) float f32x4v;

__device__ __forceinline__ float sigf(float x) { return 1.0f / (1.0f + expf(-x)); }

__device__ __forceinline__ unsigned short f2bf(float x) {      // RNE
  unsigned int b = __float_as_uint(x);
  b += 0x7FFFu + ((b >> 16) & 1u);
  return (unsigned short)(b >> 16);
}
__device__ __forceinline__ float bf2f(unsigned short u) {
  return __uint_as_float(((unsigned int)u) << 16);
}

// level-L bf16 component of x: x ~= bf1 + bf2 + bf3 + O(2^-27 x)
template<int L>
__device__ __forceinline__ unsigned short lvl_bf(float x) {
  unsigned short b1 = f2bf(x);
  if (L == 1) return b1;
  float r1 = x - bf2f(b1);
  unsigned short b2 = f2bf(r1);
  if (L == 2) return b2;
  return f2bf(r1 - bf2f(b2));
}

// ---------------------------------------------------------------------------
// prep: Wcat[r'][0..383]=w1, [384..767]=w2, [768..1151]=w3 (bf16 levels).
// Row permutation (same as round 6, proven):
//   r' = nb*128 + ch*64 + g*16 + j  <->  n = g*256 + nb*32 + ch*16 + j
// ---------------------------------------------------------------------------
__global__ void prep_weights(const float* __restrict__ eWih, const float* __restrict__ eWhh,
                             const float* __restrict__ dWih, const float* __restrict__ dWhh,
                             unsigned short* __restrict__ We, unsigned short* __restrict__ Wd)
{
  int rb = blockIdx.x;                 // 0..2047
  const float* Wih; const float* Whh; unsigned short* dst; int rp;
  if (rb < 1024) { Wih = eWih; Whh = eWhh; dst = We; rp = rb; }
  else           { Wih = dWih; Whh = dWhh; dst = Wd; rp = rb - 1024; }
  int nb = rp >> 7, rem = rp & 127, ch = rem >> 6, g = (rem >> 4) & 3, j = rem & 15;
  int n = g * H_DIM + nb * 32 + ch * 16 + j;
  unsigned short* o = dst + (size_t)rp * KW;
  for (int k = threadIdx.x; k < 384; k += 256) {
    float v = (k < E_DIM) ? Wih[(size_t)n * E_DIM + k] : Whh[(size_t)n * H_DIM + (k - E_DIM)];
    unsigned short w1 = f2bf(v);
    float r1 = v - bf2f(w1);
    unsigned short w2 = f2bf(r1);
    unsigned short w3 = f2bf(r1 - bf2f(w2));
    o[k] = w1; o[384 + k] = w2; o[768 + k] = w3;
  }
}

// stage level-L bf16 of A = [emb[idx] | h_in] into Ax (per-thread: row, q4)
template<int L>
__device__ __forceinline__ void stage_A(unsigned short* Ax,
                                        const float* __restrict__ esrc,
                                        const float* __restrict__ hsrc,
                                        int row, int q4) {
  #pragma unroll
  for (int j = 0; j < 8; ++j) {
    int kc = (q4 + j * 4) * 4;
    float4 v = *(const float4*)(esrc + kc);
    unsigned short s0 = lvl_bf<L>(v.x), s1 = lvl_bf<L>(v.y),
                   s2 = lvl_bf<L>(v.z), s3 = lvl_bf<L>(v.w);
    uint2 p; p.x = (unsigned)s0 | ((unsigned)s1 << 16);
             p.y = (unsigned)s2 | ((unsigned)s3 << 16);
    *(uint2*)&Ax[row * AP + kc] = p;
  }
  #pragma unroll
  for (int j = 0; j < 16; ++j) {
    int kc = (q4 + j * 4) * 4;
    float4 v = *(const float4*)(hsrc + kc);
    unsigned short s0 = lvl_bf<L>(v.x), s1 = lvl_bf<L>(v.y),
                   s2 = lvl_bf<L>(v.z), s3 = lvl_bf<L>(v.w);
    uint2 p; p.x = (unsigned)s0 | ((unsigned)s1 << 16);
             p.y = (unsigned)s2 | ((unsigned)s3 << 16);
    *(uint2*)&Ax[row * AP + E_DIM + kc] = p;
  }
}

// ---------------------------------------------------------------------------
// LSTM step, bf16 triple-split 6-term MFMA.
// Grid (B/64, H/32) = (32,8), 256 thr = 4 waves. Wave (wm,wc): rows wm*32..+31,
// hidden cols wc*16..+15 (x4 gates). 36 K-tiles of 64:
//   group1 (A=a1): W k 0..1151 (w1,w2,w3)   tiles  0..17
//   group2 (A=a2): W k 0..767  (w1,w2)      tiles 18..29
//   group3 (A=a3): W k 0..383  (w1)         tiles 30..35
// All terms accumulate into the same f32 acc (no scaling needed).
// ---------------------------------------------------------------------------
__launch_bounds__(256)
__global__ void lstm_mfma_kernel(const float* __restrict__ emb,
                                 const int* __restrict__ idx_src, int idx_stride, int idx_off,
                                 const unsigned short* __restrict__ Wcat,   // [1024][1152]
                                 const float* __restrict__ bih, const float* __restrict__ bhh,
                                 const float* __restrict__ h_in,
                                 float* __restrict__ h_out, float* __restrict__ c)
{
  __shared__ unsigned short Ax[64 * AP];        // one split level at a time
  __shared__ unsigned short Bt[2][128 * BP];
  __shared__ int ridx[64];

  const int tid = threadIdx.x;
  const int m0 = blockIdx.x * 64;
  const int nb = blockIdx.y;

  if (tid < 64) ridx[tid] = idx_src[(size_t)(m0 + tid) * idx_stride + idx_off];
  __syncthreads();

  const int arow = tid >> 2;
  const int q4   = tid & 3;
  const float* esrc = emb + (size_t)ridx[arow] * E_DIM;
  const float* hsrc = h_in + (size_t)(m0 + arow) * H_DIM;

  stage_A<1>(Ax, esrc, hsrc, arow, q4);

  // ---- B stage tile 0
  const int brow0 = tid >> 2;
  const int bsg   = tid & 3;
  const unsigned short* wbase = Wcat + (size_t)(nb * 128) * KW;
  #pragma unroll
  for (int p = 0; p < 2; ++p) {
    int rowb = brow0 + p * 64;
    const unsigned short* src = wbase + (size_t)rowb * KW;
    uint4 v0 = *(const uint4*)(src + bsg * 8);
    uint4 v1 = *(const uint4*)(src + (bsg + 4) * 8);
    *(uint4*)&Bt[0][rowb * BP + bsg * 8] = v0;
    *(uint4*)&Bt[0][rowb * BP + (bsg + 4) * 8] = v1;
  }
  __syncthreads();

  const int wm = (tid >> 6) & 1;
  const int wc = tid >> 7;
  const int lr = tid & 15;
  const int l4 = (tid & 63) >> 4;

  f32x4v acc[2][4];
  #pragma unroll
  for (int mf = 0; mf < 2; ++mf)
    #pragma unroll
    for (int g = 0; g < 4; ++g)
      acc[mf][g] = (f32x4v){0.f, 0.f, 0.f, 0.f};

  // tile i -> W k-offset and A k-offset
  auto wko = [](int i) { int j = (i < 18) ? i : (i < 30 ? i - 18 : i - 30); return j * 64; };
  auto ako = [](int i) { int j = (i < 18) ? i : (i < 30 ? i - 18 : i - 30); return (j % 6) * 64; };

  auto run_tiles = [&](int i0, int i1) {
    #pragma unroll 1
    for (int i = i0; i < i1; ++i) {
      const int bf = i & 1;
      uint4 pv[4];
      const bool pf = (i < 35);
      if (pf) {
        const int ko = wko(i + 1);
        #pragma unroll
        for (int p = 0; p < 2; ++p) {
          int rowb = brow0 + p * 64;
          const unsigned short* src = wbase + (size_t)rowb * KW + ko;
          pv[p * 2 + 0] = *(const uint4*)(src + bsg * 8);
          pv[p * 2 + 1] = *(const uint4*)(src + (bsg + 4) * 8);
        }
      }
      const int akb = ako(i);
      #pragma unroll
      for (int kh = 0; kh < 2; ++kh) {
        const int kk = kh * 32 + l4 * 8;
        bf16x8v af0 = *(const bf16x8v*)&Ax[(wm * 32 + lr) * AP + akb + kk];
        bf16x8v af1 = *(const bf16x8v*)&Ax[(wm * 32 + 16 + lr) * AP + akb + kk];
        #pragma unroll
        for (int g = 0; g < 4; ++g) {
          bf16x8v bfr = *(const bf16x8v*)&Bt[bf][(wc * 64 + g * 16 + lr) * BP + kk];
          acc[0][g] = __builtin_amdgcn_mfma_f32_16x16x32_bf16(af0, bfr, acc[0][g], 0, 0, 0);
          acc[1][g] = __builtin_amdgcn_mfma_f32_16x16x32_bf16(af1, bfr, acc[1][g], 0, 0, 0);
        }
      }
      if (pf) {
        #pragma unroll
        for (int p = 0; p < 2; ++p) {
          int rowb = brow0 + p * 64;
          *(uint4*)&Bt[bf ^ 1][rowb * BP + bsg * 8] = pv[p * 2 + 0];
          *(uint4*)&Bt[bf ^ 1][rowb * BP + (bsg + 4) * 8] = pv[p * 2 + 1];
        }
      }
      __syncthreads();
    }
  };

  run_tiles(0, 18);                 // a1 x (w1,w2,w3)
  stage_A<2>(Ax, esrc, hsrc, arow, q4);   // sources L1-hot; rewrite Ax
  __syncthreads();
  run_tiles(18, 30);                // a2 x (w1,w2)
  stage_A<3>(Ax, esrc, hsrc, arow, q4);
  __syncthreads();
  run_tiles(30, 36);                // a3 x w1

  // ---- epilogue: bias + cell update (lane owns all 4 gates of its (row,col))
  const int col = nb * 32 + wc * 16 + lr;
  float bs[4];
  #pragma unroll
  for (int g = 0; g < 4; ++g) bs[g] = bih[g * H_DIM + col] + bhh[g * H_DIM + col];

  #pragma unroll
  for (int mf = 0; mf < 2; ++mf) {
    #pragma unroll
    for (int r = 0; r < 4; ++r) {
      int row = m0 + wm * 32 + mf * 16 + l4 * 4 + r;
      float zi = acc[mf][0][r] + bs[0];
      float zf = acc[mf][1][r] + bs[1];
      float zg = acc[mf][2][r] + bs[2];
      float zo = acc[mf][3][r] + bs[3];
      float co = c[(size_t)row * H_DIM + col];
      float cn = sigf(zf) * co + sigf(zi) * tanhf(zg);
      c[(size_t)row * H_DIM + col] = cn;
      h_out[(size_t)row * H_DIM + col] = sigf(zo) * tanhf(cn);
    }
  }
}

// ---------------------------------------------------------------------------
// declog — EXACT round-2 version (known-good): logits + argmax fused.
// ---------------------------------------------------------------------------
__launch_bounds__(256)
__global__ void declog_kernel(const float* __restrict__ h,    // [B, H]
                              const float* __restrict__ fcW,  // [V, H]
                              const float* __restrict__ fcb,  // [V]
                              float* __restrict__ out,        // [B, T, V]
                              int* __restrict__ tok,          // [B]
                              int t, int T)
{
  __shared__ float As[8][264];
  __shared__ float Bs[16][V_DIM];

  const int tid  = threadIdx.x;
  const int lane = tid & 63;
  const int wv   = tid >> 6;
  const int r0   = blockIdx.x * 8;

  #pragma unroll
  for (int s = 0; s < 2; ++s) {
    int f4 = s * 256 + tid;
    int row = f4 >> 6, q = f4 & 63;
    float4 v = *(const float4*)(h + (size_t)(r0 + row) * H_DIM + q * 4);
    *(float4*)&As[row][q * 4] = v;
  }

  float acc[2][8] = {};
  const int v0 = tid * 2;

  for (int k0 = 0; k0 < H_DIM; k0 += 16) {
    __syncthreads();
    #pragma unroll
    for (int s = 0; s < 2; ++s) {
      const float* src = fcW + (size_t)(v0 + s) * H_DIM + k0;
      float4 w0 = *(const float4*)(src + 0);
      float4 w1 = *(const float4*)(src + 4);
      float4 w2 = *(const float4*)(src + 8);
      float4 w3 = *(const float4*)(src + 12);
      float w[16] = {w0.x, w0.y, w0.z, w0.w, w1.x, w1.y, w1.z, w1.w,
                     w2.x, w2.y, w2.z, w2.w, w3.x, w3.y, w3.z, w3.w};
      #pragma unroll
      for (int q = 0; q < 16; ++q) Bs[q][v0 + s] = w[q];
    }
    __syncthreads();

    #pragma unroll
    for (int kk = 0; kk < 16; ++kk) {
      float a0 = As[wv * 2 + 0][k0 + kk];
      float a1 = As[wv * 2 + 1][k0 + kk];
      #pragma unroll
      for (int i = 0; i < 8; ++i) {
        float b = Bs[kk][lane + 64 * i];
        acc[0][i] = fmaf(a0, b, acc[0][i]);
        acc[1][i] = fmaf(a1, b, acc[1][i]);
      }
    }
  }

  float bias[8];
  #pragma unroll
  for (int i = 0; i < 8; ++i) bias[i] = fcb[lane + 64 * i];

  #pragma unroll
  for (int r = 0; r < 2; ++r) {
    int row = r0 + wv * 2 + r;
    float* op = out + (size_t)row * T * V_DIM + (size_t)t * V_DIM;
    float best = -INFINITY;
    int   bi   = 0x7fffffff;
    #pragma unroll
    for (int i = 0; i < 8; ++i) {
      float x = acc[r][i] + bias[i];
      op[lane + 64 * i] = x;
      if (x > best) { best = x; bi = lane + 64 * i; }
    }
    #pragma unroll
    for (int off = 32; off; off >>= 1) {
      float ov = __shfl_xor(best, off);
      int   oi = __shfl_xor(bi, off);
      if (ov > best || (ov == best && oi < bi)) { best = ov; bi = oi; }
    }
    if (lane == 0) tok[row] = bi;
  }
}

extern "C" void kernel_launch(void* const* d_in, const int* in_sizes, int n_in,
                              void* d_out, int out_size, void* d_ws, size_t ws_size,
                              hipStream_t stream) {
  const int*   source  = (const int*)d_in[0];
  const float* enc_emb = (const float*)d_in[2];
  const float* enc_Wih = (const float*)d_in[3];
  const float* enc_Whh = (const float*)d_in[4];
  const float* enc_bih = (const float*)d_in[5];
  const float* enc_bhh = (const float*)d_in[6];
  const float* dec_emb = (const float*)d_in[7];
  const float* dec_Wih = (const float*)d_in[8];
  const float* dec_Whh = (const float*)d_in[9];
  const float* dec_bih = (const float*)d_in[10];
  const float* dec_bhh = (const float*)d_in[11];
  const float* fc_W    = (const float*)d_in[12];
  const float* fc_b    = (const float*)d_in[13];
  float* out = (float*)d_out;

  const int B = in_sizes[0] / S_LEN;              // 2048
  const int T = out_size / (B * V_DIM);           // 48

  const size_t BH = (size_t)B * H_DIM;
  float* h0  = (float*)d_ws;
  float* h1  = h0 + BH;
  float* c   = h1 + BH;
  int*   tok = (int*)(c + BH);
  unsigned short* We = (unsigned short*)(tok + B);
  unsigned short* Wd = We + (size_t)1024 * KW;

  hipMemsetAsync(h0,  0, BH * sizeof(float), stream);
  hipMemsetAsync(c,   0, BH * sizeof(float), stream);
  hipMemsetAsync(tok, 0, (size_t)B * sizeof(int), stream);

  prep_weights<<<dim3(2048), dim3(256), 0, stream>>>(
      enc_Wih, enc_Whh, dec_Wih, dec_Whh, We, Wd);

  dim3 blk(256);
  dim3 g_lstm(B / 64, H_DIM / 32);    // (32, 8) = 256 blocks
  dim3 g_declog(B / 8);               // 256 blocks

  const float* hin = h0;
  float* hout = h1;

  // ---- encoder ----
  for (int s = 0; s < S_LEN; ++s) {
    lstm_mfma_kernel<<<g_lstm, blk, 0, stream>>>(
        enc_emb, source, S_LEN, s, We, enc_bih, enc_bhh, hin, hout, c);
    const float* tmp = hout; hout = (float*)hin; hin = tmp;
  }

  // ---- decoder (greedy, autoregressive) ----
  for (int t = 0; t < T; ++t) {
    lstm_mfma_kernel<<<g_lstm, blk, 0, stream>>>(
        dec_emb, tok, 1, 0, Wd, dec_bih, dec_bhh, hin, hout, c);
    const float* tmp = hout; hout = (float*)hin; hin = tmp;
    declog_kernel<<<g_declog, blk, 0, stream>>>(hin, fc_W, fc_b, out, tok, t, T);
  }
}

// Round 8
// 4254.206 us; speedup vs baseline: 4.2944x; 1.5315x over previous
//
#include <hip/hip_runtime.h>
#include <cmath>

#define S_LEN 32
#define E_DIM 128
#define H_DIM 256
#define V_DIM 512
#define AP    392           // A LDS pitch (shorts) -> 784 B (round-7 proven)
#define NTILE 18            // BK=128: pass1 9 (a1 x w1w2w3), pass2 6, pass3 3
#define TILE_SHORTS 16384   // 32 frags x 64 lanes x 8 shorts = 32 KB

typedef __attribute__((ext_vector_type(8))) short bf16x8v;
typedef __attribute__((ext_vector_type(4))) float f32x4v;

__device__ __forceinline__ float sigf(float x) { return 1.0f / (1.0f + expf(-x)); }

__device__ __forceinline__ unsigned short f2bf(float x) {      // RNE
  unsigned int b = __float_as_uint(x);
  b += 0x7FFFu + ((b >> 16) & 1u);
  return (unsigned short)(b >> 16);
}
__device__ __forceinline__ float bf2f(unsigned short u) {
  return __uint_as_float(((unsigned int)u) << 16);
}

template<int L>
__device__ __forceinline__ unsigned short lvl_bf(float x) {
  unsigned short b1 = f2bf(x);
  if (L == 1) return b1;
  float r1 = x - bf2f(b1);
  unsigned short b2 = f2bf(r1);
  if (L == 2) return b2;
  return f2bf(r1 - bf2f(b2));
}

__device__ __forceinline__ void gll16(const unsigned short* g, unsigned short* l) {
  __builtin_amdgcn_global_load_lds(
      (const __attribute__((address_space(1))) unsigned int*)g,
      (__attribute__((address_space(3))) unsigned int*)l, 16, 0, 0);
}

// ---------------------------------------------------------------------------
// prep: write W in the EXACT fragment-stream order the lstm kernel consumes.
// Layout: [set][nb 0..7][tile j 0..17][fi 0..31][lane 0..63][8 shorts]
//   fi = kh*8 + wc*4 + g ; lane l supplies row n = g*256+nb*32+wc*16+(l&15),
//   split-k sk = jj*128 + kh*32 + (l>>4)*8 + e  (jj = in-pass tile idx),
//   level = sk/384 (bf16 split level 1..3), kk = sk%384 (0..127 Wih, rest Whh).
// ---------------------------------------------------------------------------
__global__ void prep_weights(const float* __restrict__ eWih, const float* __restrict__ eWhh,
                             const float* __restrict__ dWih, const float* __restrict__ dWhh,
                             unsigned short* __restrict__ We, unsigned short* __restrict__ Wd)
{
  const int b    = blockIdx.x;            // 0..287
  const int j    = b % NTILE;
  const int rest = b / NTILE;
  const int nb   = rest & 7;
  const int set  = rest >> 3;
  const float* Wih = set ? dWih : eWih;
  const float* Whh = set ? dWhh : eWhh;
  unsigned short* dst = (set ? Wd : We) + ((size_t)nb * NTILE + j) * TILE_SHORTS;
  const int jj = (j < 9) ? j : (j < 15 ? j - 9 : j - 15);

  for (int cpos = threadIdx.x; cpos < 2048; cpos += 256) {
    int fi = cpos >> 6, l = cpos & 63;
    int kh = fi >> 3, wc = (fi >> 2) & 1, g = fi & 3;
    int n   = g * H_DIM + nb * 32 + wc * 16 + (l & 15);
    int sk0 = jj * 128 + kh * 32 + (l >> 4) * 8;
    int lvl = sk0 / 384;                  // uniform for the 8-elem chunk
    int kk  = sk0 - lvl * 384;
    unsigned short o8[8];
    #pragma unroll
    for (int e = 0; e < 8; ++e) {
      int k = kk + e;
      float v = (k < E_DIM) ? Wih[(size_t)n * E_DIM + k]
                            : Whh[(size_t)n * H_DIM + (k - E_DIM)];
      unsigned short b1 = f2bf(v);
      float r1 = v - bf2f(b1);
      unsigned short b2 = f2bf(r1);
      unsigned short b3 = f2bf(r1 - bf2f(b2));
      o8[e] = (lvl == 0) ? b1 : (lvl == 1) ? b2 : b3;
    }
    uint4 pk;
    pk.x = (unsigned)o8[0] | ((unsigned)o8[1] << 16);
    pk.y = (unsigned)o8[2] | ((unsigned)o8[3] << 16);
    pk.z = (unsigned)o8[4] | ((unsigned)o8[5] << 16);
    pk.w = (unsigned)o8[6] | ((unsigned)o8[7] << 16);
    *(uint4*)&dst[(size_t)cpos * 8] = pk;
  }
}

// stage level-L bf16 of A = [emb[idx] | h_in] into Ax — EXACT round-7 version
template<int L>
__device__ __forceinline__ void stage_A(unsigned short* Ax,
                                        const float* __restrict__ esrc,
                                        const float* __restrict__ hsrc,
                                        int row, int q4) {
  #pragma unroll
  for (int j = 0; j < 8; ++j) {
    int kc = (q4 + j * 4) * 4;
    float4 v = *(const float4*)(esrc + kc);
    unsigned short s0 = lvl_bf<L>(v.x), s1 = lvl_bf<L>(v.y),
                   s2 = lvl_bf<L>(v.z), s3 = lvl_bf<L>(v.w);
    uint2 p; p.x = (unsigned)s0 | ((unsigned)s1 << 16);
             p.y = (unsigned)s2 | ((unsigned)s3 << 16);
    *(uint2*)&Ax[row * AP + kc] = p;
  }
  #pragma unroll
  for (int j = 0; j < 16; ++j) {
    int kc = (q4 + j * 4) * 4;
    float4 v = *(const float4*)(hsrc + kc);
    unsigned short s0 = lvl_bf<L>(v.x), s1 = lvl_bf<L>(v.y),
                   s2 = lvl_bf<L>(v.z), s3 = lvl_bf<L>(v.w);
    uint2 p; p.x = (unsigned)s0 | ((unsigned)s1 << 16);
             p.y = (unsigned)s2 | ((unsigned)s3 << 16);
    *(uint2*)&Ax[row * AP + E_DIM + kc] = p;
  }
}

// ---------------------------------------------------------------------------
// LSTM step, bf16 triple-split 6-term MFMA (numerics IDENTICAL to round 7).
// B-path redesigned: pre-swizzled fragment stream + global_load_lds double
// buffer; B frag reads are base+lane*16 (conflict-free). 18 tiles of BK=128.
// Grid (B/64, H/32) = (32,8), 256 thr = 4 waves (wm = row-half, wc = col-half).
// ---------------------------------------------------------------------------
__launch_bounds__(256)
__global__ void lstm_mfma_kernel(const float* __restrict__ emb,
                                 const int* __restrict__ idx_src, int idx_stride, int idx_off,
                                 const unsigned short* __restrict__ Wf,   // frag stream
                                 const float* __restrict__ bih, const float* __restrict__ bhh,
                                 const float* __restrict__ h_in,
                                 float* __restrict__ h_out, float* __restrict__ c)
{
  __shared__ unsigned short Ax[64 * AP];          // 50176 B
  __shared__ unsigned short Bt[2][TILE_SHORTS];   // 65536 B
  __shared__ int ridx[64];

  const int tid  = threadIdx.x;
  const int lane = tid & 63;
  const int w    = tid >> 6;           // wave 0..3
  const int m0 = blockIdx.x * 64;
  const int nb = blockIdx.y;

  if (tid < 64) ridx[tid] = idx_src[(size_t)(m0 + tid) * idx_stride + idx_off];
  __syncthreads();

  const int arow = tid >> 2;
  const int q4   = tid & 3;
  const float* esrc = emb + (size_t)ridx[arow] * E_DIM;
  const float* hsrc = h_in + (size_t)(m0 + arow) * H_DIM;

  const unsigned short* wstream = Wf + (size_t)nb * (NTILE * TILE_SHORTS);

  // stage B-tile j into buffer bsel (each wave stages its own 8 KB, linear)
  auto stage_B = [&](int j, int bsel) {
    const unsigned short* src = wstream + (size_t)j * TILE_SHORTS + w * 4096 + lane * 8;
    unsigned short* dstp = &Bt[bsel][w * 4096];
    #pragma unroll
    for (int i = 0; i < 8; ++i) gll16(src + i * 512, dstp + i * 512);
  };

  stage_A<1>(Ax, esrc, hsrc, arow, q4);
  stage_B(0, 0);
  __syncthreads();                      // drains gll + A writes

  const int wm = (tid >> 6) & 1;
  const int wc = tid >> 7;
  const int lr = tid & 15;
  const int l4 = lane >> 4;

  f32x4v acc[2][4];
  #pragma unroll
  for (int mf = 0; mf < 2; ++mf)
    #pragma unroll
    for (int g = 0; g < 4; ++g)
      acc[mf][g] = (f32x4v){0.f, 0.f, 0.f, 0.f};

  int buf = 0;
  #pragma unroll 1
  for (int j = 0; j < NTILE; ++j) {
    if (j < NTILE - 1) stage_B(j + 1, buf ^ 1);
    const int jj  = (j < 9) ? j : (j < 15 ? j - 9 : j - 15);
    const int akb = (jj % 3) * 128;
    const unsigned short* bb = &Bt[buf][0];
    #pragma unroll
    for (int kh = 0; kh < 4; ++kh) {
      const int kk = akb + kh * 32 + l4 * 8;
      bf16x8v af0 = *(const bf16x8v*)&Ax[(wm * 32 + lr) * AP + kk];
      bf16x8v af1 = *(const bf16x8v*)&Ax[(wm * 32 + 16 + lr) * AP + kk];
      #pragma unroll
      for (int g = 0; g < 4; ++g) {
        bf16x8v bfr = *(const bf16x8v*)&bb[(kh * 8 + wc * 4 + g) * 512 + lane * 8];
        acc[0][g] = __builtin_amdgcn_mfma_f32_16x16x32_bf16(af0, bfr, acc[0][g], 0, 0, 0);
        acc[1][g] = __builtin_amdgcn_mfma_f32_16x16x32_bf16(af1, bfr, acc[1][g], 0, 0, 0);
      }
    }
    __syncthreads();                    // gll for j+1 drained; buf reads done
    if (j == 8)       { stage_A<2>(Ax, esrc, hsrc, arow, q4); __syncthreads(); }
    else if (j == 14) { stage_A<3>(Ax, esrc, hsrc, arow, q4); __syncthreads(); }
    buf ^= 1;
  }

  // ---- epilogue: bias + cell update — EXACT round-7 version
  const int col = nb * 32 + wc * 16 + lr;
  float bs[4];
  #pragma unroll
  for (int g = 0; g < 4; ++g) bs[g] = bih[g * H_DIM + col] + bhh[g * H_DIM + col];

  #pragma unroll
  for (int mf = 0; mf < 2; ++mf) {
    #pragma unroll
    for (int r = 0; r < 4; ++r) {
      int row = m0 + wm * 32 + mf * 16 + l4 * 4 + r;
      float zi = acc[mf][0][r] + bs[0];
      float zf = acc[mf][1][r] + bs[1];
      float zg = acc[mf][2][r] + bs[2];
      float zo = acc[mf][3][r] + bs[3];
      float co = c[(size_t)row * H_DIM + col];
      float cn = sigf(zf) * co + sigf(zi) * tanhf(zg);
      c[(size_t)row * H_DIM + col] = cn;
      h_out[(size_t)row * H_DIM + col] = sigf(zo) * tanhf(cn);
    }
  }
}

// ---------------------------------------------------------------------------
// declog — EXACT round-2 version (known-good): logits + argmax fused.
// ---------------------------------------------------------------------------
__launch_bounds__(256)
__global__ void declog_kernel(const float* __restrict__ h,    // [B, H]
                              const float* __restrict__ fcW,  // [V, H]
                              const float* __restrict__ fcb,  // [V]
                              float* __restrict__ out,        // [B, T, V]
                              int* __restrict__ tok,          // [B]
                              int t, int T)
{
  __shared__ float As[8][264];
  __shared__ float Bs[16][V_DIM];

  const int tid  = threadIdx.x;
  const int lane = tid & 63;
  const int wv   = tid >> 6;
  const int r0   = blockIdx.x * 8;

  #pragma unroll
  for (int s = 0; s < 2; ++s) {
    int f4 = s * 256 + tid;
    int row = f4 >> 6, q = f4 & 63;
    float4 v = *(const float4*)(h + (size_t)(r0 + row) * H_DIM + q * 4);
    *(float4*)&As[row][q * 4] = v;
  }

  float acc[2][8] = {};
  const int v0 = tid * 2;

  for (int k0 = 0; k0 < H_DIM; k0 += 16) {
    __syncthreads();
    #pragma unroll
    for (int s = 0; s < 2; ++s) {
      const float* src = fcW + (size_t)(v0 + s) * H_DIM + k0;
      float4 w0 = *(const float4*)(src + 0);
      float4 w1 = *(const float4*)(src + 4);
      float4 w2 = *(const float4*)(src + 8);
      float4 w3 = *(const float4*)(src + 12);
      float w[16] = {w0.x, w0.y, w0.z, w0.w, w1.x, w1.y, w1.z, w1.w,
                     w2.x, w2.y, w2.z, w2.w, w3.x, w3.y, w3.z, w3.w};
      #pragma unroll
      for (int q = 0; q < 16; ++q) Bs[q][v0 + s] = w[q];
    }
    __syncthreads();

    #pragma unroll
    for (int kk = 0; kk < 16; ++kk) {
      float a0 = As[wv * 2 + 0][k0 + kk];
      float a1 = As[wv * 2 + 1][k0 + kk];
      #pragma unroll
      for (int i = 0; i < 8; ++i) {
        float b = Bs[kk][lane + 64 * i];
        acc[0][i] = fmaf(a0, b, acc[0][i]);
        acc[1][i] = fmaf(a1, b, acc[1][i]);
      }
    }
  }

  float bias[8];
  #pragma unroll
  for (int i = 0; i < 8; ++i) bias[i] = fcb[lane + 64 * i];

  #pragma unroll
  for (int r = 0; r < 2; ++r) {
    int row = r0 + wv * 2 + r;
    float* op = out + (size_t)row * T * V_DIM + (size_t)t * V_DIM;
    float best = -INFINITY;
    int   bi   = 0x7fffffff;
    #pragma unroll
    for (int i = 0; i < 8; ++i) {
      float x = acc[r][i] + bias[i];
      op[lane + 64 * i] = x;
      if (x > best) { best = x; bi = lane + 64 * i; }
    }
    #pragma unroll
    for (int off = 32; off; off >>= 1) {
      float ov = __shfl_xor(best, off);
      int   oi = __shfl_xor(bi, off);
      if (ov > best || (ov == best && oi < bi)) { best = ov; bi = oi; }
    }
    if (lane == 0) tok[row] = bi;
  }
}

extern "C" void kernel_launch(void* const* d_in, const int* in_sizes, int n_in,
                              void* d_out, int out_size, void* d_ws, size_t ws_size,
                              hipStream_t stream) {
  const int*   source  = (const int*)d_in[0];
  const float* enc_emb = (const float*)d_in[2];
  const float* enc_Wih = (const float*)d_in[3];
  const float* enc_Whh = (const float*)d_in[4];
  const float* enc_bih = (const float*)d_in[5];
  const float* enc_bhh = (const float*)d_in[6];
  const float* dec_emb = (const float*)d_in[7];
  const float* dec_Wih = (const float*)d_in[8];
  const float* dec_Whh = (const float*)d_in[9];
  const float* dec_bih = (const float*)d_in[10];
  const float* dec_bhh = (const float*)d_in[11];
  const float* fc_W    = (const float*)d_in[12];
  const float* fc_b    = (const float*)d_in[13];
  float* out = (float*)d_out;

  const int B = in_sizes[0] / S_LEN;              // 2048
  const int T = out_size / (B * V_DIM);           // 48

  const size_t BH = (size_t)B * H_DIM;
  const size_t WFSZ = (size_t)8 * NTILE * TILE_SHORTS;   // shorts per weight set
  float* h0  = (float*)d_ws;
  float* h1  = h0 + BH;
  float* c   = h1 + BH;
  int*   tok = (int*)(c + BH);
  unsigned short* We = (unsigned short*)(tok + B);
  unsigned short* Wd = We + WFSZ;

  hipMemsetAsync(h0,  0, BH * sizeof(float), stream);
  hipMemsetAsync(c,   0, BH * sizeof(float), stream);
  hipMemsetAsync(tok, 0, (size_t)B * sizeof(int), stream);

  prep_weights<<<dim3(2 * 8 * NTILE), dim3(256), 0, stream>>>(
      enc_Wih, enc_Whh, dec_Wih, dec_Whh, We, Wd);

  dim3 blk(256);
  dim3 g_lstm(B / 64, H_DIM / 32);    // (32, 8) = 256 blocks
  dim3 g_declog(B / 8);               // 256 blocks

  const float* hin = h0;
  float* hout = h1;

  // ---- encoder ----
  for (int s = 0; s < S_LEN; ++s) {
    lstm_mfma_kernel<<<g_lstm, blk, 0, stream>>>(
        enc_emb, source, S_LEN, s, We, enc_bih, enc_bhh, hin, hout, c);
    const float* tmp = hout; hout = (float*)hin; hin = tmp;
  }

  // ---- decoder (greedy, autoregressive) ----
  for (int t = 0; t < T; ++t) {
    lstm_mfma_kernel<<<g_lstm, blk, 0, stream>>>(
        dec_emb, tok, 1, 0, Wd, dec_bih, dec_bhh, hin, hout, c);
    const float* tmp = hout; hout = (float*)hin; hin = tmp;
    declog_kernel<<<g_declog, blk, 0, stream>>>(hin, fc_W, fc_b, out, tok, t, T);
  }
}